// Round 10
// baseline (48.046 us; speedup 1.0000x reference)
//
#include <hip/hip_runtime.h>

// Not-a-knot cubic spline upsample (512 x 8192 f32 -> 512 x 32768 f32).
//
// Pure-register streaming kernel: NO LDS, NO barriers.
// Thread g (per row) owns outputs q = 16g..16g+15. Exact integer identities
// (q0=16g, W-1=8191, WU-1=32767 = 4*8191+3):
//   i0 = floor(q0*8191/32767) = 4g-1,  rr0 = 32767-12g   (all g in [1,2730])
// -> window y[4g-7 .. 4g+10] inside the 16B-ALIGNED range [4g-8, 4g+16):
//    6 global dwordx4 at lane-stride 16B = dense coalesced (proven pattern).
// M via 2 Green-conv seeds (K=8, R7-proven weights) + 4 recurrence steps
//   M[j-1] = d[j] - 4M[j] - M[j+1]  (amplification <= x14 on ~2e-4 -> 3e-3).
// Crossing logic per output folds to compile-time for 8/16 outputs because
// the fast branch bounds g to [3,2044] (value-range propagation).
// Stores: 4 plain f32x4 (lane-stride 64B); L2 merges quarters -> full lines.
// Edge threads (g<3 or g>2044, 6/row) use R1/R7-proven reflected-RHS conv.

typedef float f32x4 __attribute__((ext_vector_type(4)));

constexpr int W  = 8192;
constexpr int WU = 32768;

constexpr float Rr  = -0.26794919243112270647f;  // sqrt(3)-2
constexpr float W0c = -4.39230484541326386f;     // 12C(r-1)
constexpr float W1c =  2.78460969082652752f;     // 6C(1-r)^2
constexpr float Cg  =  0.288675134594812882f;    // C = 1/(2 sqrt(3))

__device__ __forceinline__ float convg(const float* __restrict__ xr, int j,
                                       float M1g, float Mn2g) {
    // b-space Green conv with odd reflection about -1 and n, K=10 (R1-proven).
    const int n = W - 4;
    auto bg = [&](int m) -> float {
        if (m == -1 || m == n) return 0.f;
        float sgn = 1.f;
        if (m < -1)      { m = -2 - m;   sgn = -1.f; }
        else if (m > n)  { m = 2*n - m;  sgn = -1.f; }
        int p = m + 2;
        float v = 6.f * (xr[p+1] - 2.f*xr[p] + xr[p-1]);
        if (m == 0)     v -= M1g;
        if (m == n - 1) v -= Mn2g;
        return sgn * v;
    };
    const int mc = j - 2;
    float acc = Cg * bg(mc);
    float wr  = Cg;
    #pragma unroll
    for (int d = 1; d <= 10; ++d) {
        wr  *= Rr;
        acc += wr * (bg(mc - d) + bg(mc + d));
    }
    return acc;
}

__global__ __launch_bounds__(256)
void spline_kernel(const float* __restrict__ x, float* __restrict__ out)
{
    const int gid = blockIdx.x * 256 + threadIdx.x;
    const int r   = gid >> 11;                   // 2048 threads per row
    const int g   = gid & 2047;
    const float* __restrict__ xr = x + (size_t)r * W;

    float C0[5], C1[5], C2[5], C3[5];

    if (g >= 3 && g <= 2044) {
        // ---- fast path: dense aligned window, seeds + recurrence ----
        float w[24];                             // w[m] = y[4g-8+m]
        const float* base = xr + 4*g - 8;        // 16B-aligned
        #pragma unroll
        for (int k = 0; k < 6; ++k) {
            f32x4 v = *(const f32x4*)(base + 4*k);
            w[4*k]=v.x; w[4*k+1]=v.y; w[4*k+2]=v.z; w[4*k+3]=v.w;
        }
        // Seeds: M at knots 4g+1 (center w[9]) and 4g+2 (center w[10]), K=8.
        float m2 = W0c * w[9], m3 = W0c * w[10];
        float wd = W1c;
        #pragma unroll
        for (int d = 1; d <= 8; ++d) {
            m2 += wd * (w[9 - d] + w[9 + d]);
            m3 += wd * (w[10 - d] + w[10 + d]);
            wd *= Rr;                            // folds to literals
        }
        // d[j] = 6(y[j+1]-2y[j]+y[j-1]) at j = 4g..4g+3
        float d0 = 6.f*(w[9]  - 2.f*w[8]  + w[7]);
        float d1 = 6.f*(w[10] - 2.f*w[9]  + w[8]);
        float d2 = 6.f*(w[11] - 2.f*w[10] + w[9]);
        float d3 = 6.f*(w[12] - 2.f*w[11] + w[10]);
        float M[6];                              // M at knots i0..i0+5
        M[2] = m2; M[3] = m3;
        M[1] = d1 - 4.f*m2 - m3;                 // backward
        M[0] = d0 - 4.f*M[1] - m2;
        M[4] = d2 - 4.f*m3 - m2;                 // forward
        M[5] = d3 - 4.f*M[4] - m3;
        #pragma unroll
        for (int c = 0; c < 5; ++c) {            // intervals i0..i0+4
            float y0 = w[7 + c], y1 = w[8 + c];
            C0[c] = y0;
            C1[c] = (y1 - y0) - (2.f*M[c] + M[c+1]) * (1.f/6.f);
            C2[c] = 0.5f * M[c];
            C3[c] = (M[c+1] - M[c]) * (1.f/6.f);
        }
        // ---- eval: t = A(up) - g*(12/32767); coeff pair select by up ----
        const float gf12 = (float)(12 * g);
        float* __restrict__ op = out + (size_t)r * WU + 16*g;
        #pragma unroll
        for (int s = 0; s < 4; ++s) {
            float res[4];
            #pragma unroll
            for (int v = 0; v < 4; ++v) {
                const int u  = 4*s + v;
                const int RU = (8191*u) % 32767;       // compile-time
                const int BU = (8191*u) / 32767;
                const bool up = (gf12 <= (float)RU);   // folds for 8 of 16 u
                const float A0f = (float)RU * (1.f/32767.f);
                const float A1f = 1.f + A0f;
                float t  = (up ? A0f : A1f) - gf12 * (1.f/32767.f/12.f*12.f) * (1.f/12.f*12.f);
                // (simplify: t = A - g*12/32767)
                t = (up ? A0f : A1f) - gf12 * (1.f/32767.f);
                float k0 = up ? C0[BU+1] : C0[BU];
                float k1 = up ? C1[BU+1] : C1[BU];
                float k2 = up ? C2[BU+1] : C2[BU];
                float k3 = up ? C3[BU+1] : C3[BU];
                res[v] = k0 + t * (k1 + t * (k2 + t * k3));
            }
            *(f32x4*)(op + 4*s) = (f32x4){res[0], res[1], res[2], res[3]};
        }
    } else {
        // ---- edge threads: reflected-RHS route (R1/R7-proven) ----
        const unsigned num = (unsigned)(16*g) * 8191u;
        const unsigned i0u = num / 32767u;
        const unsigned rr0 = num - i0u * 32767u;
        const int i0 = (int)i0u;
        const float M1g  = xr[0]   - 2.f*xr[1]   + xr[2];
        const float Mn2g = xr[W-1] - 2.f*xr[W-2] + xr[W-3];
        float Y[6], M[6];
        #pragma unroll
        for (int k = 0; k < 6; ++k) {
            int j = i0 + k; if (j > W-1) j = W-1;
            Y[k] = xr[j];
            float m;
            if (j == 0)        m = 2.f*M1g  - convg(xr, 2,   M1g, Mn2g);
            else if (j == 1)   m = M1g;
            else if (j == W-2) m = Mn2g;
            else if (j == W-1) m = 2.f*Mn2g - convg(xr, W-3, M1g, Mn2g);
            else               m = convg(xr, j, M1g, Mn2g);
            M[k] = m;
        }
        #pragma unroll
        for (int c = 0; c < 5; ++c) {
            C0[c] = Y[c];
            C1[c] = (Y[c+1] - Y[c]) - (2.f*M[c] + M[c+1]) * (1.f/6.f);
            C2[c] = 0.5f * M[c];
            C3[c] = (M[c+1] - M[c]) * (1.f/6.f);
        }
        float* __restrict__ op = out + (size_t)r * WU + 16*g;
        #pragma unroll
        for (int s = 0; s < 4; ++s) {
            float res[4];
            #pragma unroll
            for (int v = 0; v < 4; ++v) {
                const int u = 4*s + v;
                unsigned N  = rr0 + 8191u * (unsigned)u;
                unsigned cu = N / 32767u;              // 0..4 (magic-div)
                float t = (float)(N - cu * 32767u) * (1.f/32767.f);
                float k0 = C0[0], k1 = C1[0], k2 = C2[0], k3 = C3[0];
                #pragma unroll
                for (int c = 1; c < 5; ++c) {
                    bool sel = (cu >= (unsigned)c);
                    k0 = sel ? C0[c] : k0;
                    k1 = sel ? C1[c] : k1;
                    k2 = sel ? C2[c] : k2;
                    k3 = sel ? C3[c] : k3;
                }
                res[v] = k0 + t * (k1 + t * (k2 + t * k3));
            }
            *(f32x4*)(op + 4*s) = (f32x4){res[0], res[1], res[2], res[3]};
        }
    }
}

extern "C" void kernel_launch(void* const* d_in, const int* in_sizes, int n_in,
                              void* d_out, int out_size, void* d_ws, size_t ws_size,
                              hipStream_t stream) {
    const float* x = (const float*)d_in[0];
    float* out = (float*)d_out;
    const int B = in_sizes[0] / W;               // 512 rows
    const int nthreads = B * 2048;               // 1,048,576
    dim3 grid(nthreads / 256), block(256);
    hipLaunchKernelGGL(spline_kernel, grid, block, 0, stream, x, out);
}

// Round 11
// 24.045 us; speedup vs baseline: 1.9982x; 1.9982x over previous
//
#include <hip/hip_runtime.h>

// Not-a-knot cubic spline upsample (512 x 8192 f32 -> 512 x 32768 f32).
//
// R9 structure (best: 24.9us) + exact-index eval + packed f32x4 coeffs.
// 2048 blocks (8/CU) x 4 pipelined tiles. Per tile: conv -> barrier ->
// stage-write next tile -> eval -> barrier.
//
// Exact integer identities (q0 = 4h, W-1 = 8191, WU-1 = 32767):
//   i0 = h-1, rem = 32767 - 3h; output u in [0,4): crossing <=> 8191u >= 3h
//   (u=3 always crosses; u=0 only at h=0). All t's exact in fp32.
// Coeff LDS: Cc[skew(idx)] = (C0,C1,C2,C3) for interval s0-1+idx;
// eval reads Cc[j], Cc[j+1] (2 x ds_read_b128 per 4 outputs).
// Conv K=8 Green weights (R7/R9-proven): M[j] = W0*y[j]+sum W1 r^(d-1)(..).
// Boundary tiles (0,15): reflected-RHS b-space conv (R1-proven), K=10.

typedef float f32x4 __attribute__((ext_vector_type(4)));

constexpr int W    = 8192;
constexpr int WU   = 32768;
constexpr int TILE = 512;
constexpr int TPB  = 4;
constexpr int HL   = 16;
constexpr int YSN  = 544;            // ys[idx] = y[s0-16+idx]
constexpr int CN   = 513;            // intervals s0-1 .. s0+511
constexpr int CCN  = 578;            // skewed size: 512+64+pad
constexpr int KB   = 10;
constexpr int BTN  = 538;
constexpr int MTN  = 520;            // Mtmp, 514 used

constexpr float Rr  = -0.26794919243112270647f;  // sqrt(3)-2
constexpr float W0c = -4.39230484541326386f;
constexpr float W1c =  2.78460969082652752f;
constexpr float Cg  =  0.288675134594812882f;

__device__ __forceinline__ int skew(int i) { return i + (i >> 3); }

__global__ __launch_bounds__(256)
void spline_kernel(const float* __restrict__ x, float* __restrict__ out)
{
    const int row = blockIdx.y;
    const int t0  = blockIdx.x * TPB;
    const int tid = threadIdx.x;
    const int n   = W - 4;

    const float* __restrict__ xr   = x   + (size_t)row * W;
    float*       __restrict__ orow = out + (size_t)row * WU;

    __shared__ __align__(16) float ys[2][YSN];
    __shared__ __align__(16) f32x4 Cc[CCN];
    __shared__ float bt[BTN];
    __shared__ float Mtmp[MTN];

    auto LOAD = [&](int tile) -> f32x4 {
        f32x4 v = {0.f, 0.f, 0.f, 0.f};
        if (tid < 136) {
            int base = tile * TILE - HL + 4 * tid;
            if (tile == 0 || tile == 15) {
                #pragma unroll
                for (int e = 0; e < 4; ++e) {
                    int g = base + e;
                    g = g < 0 ? 0 : (g > W - 1 ? W - 1 : g);
                    v[e] = xr[g];
                }
            } else {
                v = *(const f32x4*)(xr + base);
            }
        }
        return v;
    };

    f32x4 regA = LOAD(t0);
    if (tid < 136) *(f32x4*)&ys[0][4 * tid] = regA;
    __syncthreads();
    regA = LOAD(t0 + 1);

    int cur = 0;
    for (int k = 0; k < TPB; ++k) {
        const int tile = t0 + k;
        const int s0   = tile * TILE;

        f32x4 regB = {0.f, 0.f, 0.f, 0.f};
        if (k + 2 < TPB) regB = LOAD(t0 + k + 2);

        float* ysc = ys[cur];
        const bool boundary = (tile == 0) || (tile == 15);

        if (!boundary) {
            // ---- interior conv: 5 M's, up-to-4 coeff sets per thread ----
            if (tid < 129) {
                const f32x4* ys4 = (const f32x4*)ysc;
                float w[24];                     // w[m] = ysc[4*tid + 4 + m]
                #pragma unroll
                for (int kk = 0; kk < 6; ++kk) {
                    f32x4 v = ys4[tid + 1 + kk];
                    w[4*kk+0]=v.x; w[4*kk+1]=v.y; w[4*kk+2]=v.z; w[4*kk+3]=v.w;
                }
                float a[5];                      // M at knot s0-1+4*tid+d
                #pragma unroll
                for (int d = 0; d < 5; ++d) a[d] = W0c * w[11 + d];
                float wd = W1c;
                #pragma unroll
                for (int dd = 1; dd <= 8; ++dd) {
                    #pragma unroll
                    for (int d = 0; d < 5; ++d)
                        a[d] += wd * (w[11 + d - dd] + w[11 + d + dd]);
                    wd *= Rr;                    // folds to literals
                }
                const int nc = (tid == 128) ? 1 : 4;
                #pragma unroll
                for (int c = 0; c < 4; ++c) {
                    if (c < nc) {
                        float y0 = w[11 + c], y1 = w[12 + c];
                        f32x4 cc = {y0,
                                    (y1 - y0) - (2.f*a[c] + a[c+1]) * (1.f/6.f),
                                    0.5f * a[c],
                                    (a[c+1] - a[c]) * (1.f/6.f)};
                        Cc[skew(4 * tid + c)] = cc;
                    }
                }
            }
        } else {
            // ---- boundary: reflected-RHS M (R1-proven), then coeffs ----
            const int YS0 = s0 - HL;
            auto Dp = [&](int p) -> float {
                int a2 = p - YS0;
                return 6.0f * (ysc[a2+1] - 2.0f*ysc[a2] + ysc[a2-1]);
            };
            auto M1v = [&]() -> float {
                int a2 = -YS0; return ysc[a2] - 2.f*ysc[a2+1] + ysc[a2+2];
            };
            auto Mn2v = [&]() -> float {
                int a2 = (W-1) - YS0; return ysc[a2] - 2.f*ysc[a2-1] + ysc[a2-2];
            };
            auto bval = [&](int m) -> float {
                if (m == -1 || m == n) return 0.f;
                float sgn = 1.f;
                if (m < -1)     { m = -2 - m;    sgn = -1.f; }
                else if (m > n) { m = 2*n - m;   sgn = -1.f; }
                float v = Dp(m + 2);
                if (m == 0)     v -= M1v();
                if (m == n - 1) v -= Mn2v();
                return sgn * v;
            };
            const int BT0 = s0 - 3 - KB;
            for (int idx = tid; idx < BTN; idx += 256)
                bt[idx] = bval(BT0 + idx);
            __syncthreads();
            auto convb = [&](int j) -> float {
                int base = j - 2 - BT0;
                float acc = Cg * bt[base];
                float wr  = Cg;
                #pragma unroll
                for (int d = 1; d <= KB; ++d) {
                    wr  *= Rr;
                    acc += wr * (bt[base-d] + bt[base+d]);
                }
                return acc;
            };
            for (int idx = tid; idx < 514; idx += 256) {
                int j = s0 - 1 + idx;
                j = j < 0 ? 0 : (j > W-1 ? W-1 : j);
                float m;
                if (j == 0)        m = 2.f*M1v()  - convb(2);
                else if (j == 1)   m = M1v();
                else if (j == W-2) m = Mn2v();
                else if (j == W-1) m = 2.f*Mn2v() - convb(W-3);
                else               m = convb(j);
                Mtmp[idx] = m;
            }
            __syncthreads();
            for (int idx = tid; idx < CN; idx += 256) {
                float y0 = ysc[idx + 15], y1 = ysc[idx + 16];
                float m0 = Mtmp[idx], m1 = Mtmp[idx + 1];
                f32x4 cc = {y0,
                            (y1 - y0) - (2.f*m0 + m1) * (1.f/6.f),
                            0.5f * m0,
                            (m1 - m0) * (1.f/6.f)};
                Cc[skew(idx)] = cc;
            }
        }
        __syncthreads();                          // coeffs ready; ysc free

        // ---- stage next tile's y into the other buffer (drains under eval)
        if (k + 1 < TPB) {
            if (tid < 136) *(f32x4*)&ys[cur ^ 1][4 * tid] = regA;
        }

        // ---- eval: exact indices; 2 x ds_read_b128 per 4 outputs ----
        #pragma unroll
        for (int it = 0; it < 2; ++it) {
            const int j = tid + 256 * it;         // coeff idx; interval s0-1+j
            const int h = s0 + j;                 // q0 = 4h
            const int e = 32767 - 3 * h;
            f32x4 cA = Cc[skew(j)];
            f32x4 cB = Cc[skew(j + 1)];
            float res[4];
            #pragma unroll
            for (int u = 0; u < 4; ++u) {
                const int N = e + 8191 * u;
                const bool cross = (u == 3) ? true : (N >= 32767);
                float t = (float)(N - (cross ? 32767 : 0)) * (1.f/32767.f);
                f32x4 cc = cross ? cB : cA;
                res[u] = cc.x + t * (cc.y + t * (cc.z + t * cc.w));
            }
            *(f32x4*)(orow + 4 * h) = (f32x4){res[0], res[1], res[2], res[3]};
        }
        __syncthreads();                          // Cc reads + ys writes done
        regA = regB;
        cur ^= 1;
    }
}

extern "C" void kernel_launch(void* const* d_in, const int* in_sizes, int n_in,
                              void* d_out, int out_size, void* d_ws, size_t ws_size,
                              hipStream_t stream) {
    const float* x = (const float*)d_in[0];
    float* out = (float*)d_out;
    const int B = in_sizes[0] / W;               // 512 rows
    dim3 grid(W / TILE / TPB, B), block(256);    // 2048 blocks
    hipLaunchKernelGGL(spline_kernel, grid, block, 0, stream, x, out);
}